// Round 10
// baseline (373.261 us; speedup 1.0000x reference)
//
#include <hip/hip_runtime.h>
#include <cmath>

#define N_NODES 100000
#define N_EDGES 3200000
#define IN_DIM 256
#define EMB 64
#define BATCH 4096
#define MWAVES 6250        // 100000 rows / 16 per wave (gemm)
#define NBUCK 782          // ceil(100000 / 128) row-buckets
#define BROWS 128          // rows per bucket
#define BSTRIDE 4608       // u64 slots per bucket (mean 4096 + 8 sigma), %8==0
#define EPB 4096           // edges per passA sub-block
#define GSUB 782           // gemm sub-blocks (ceil(6250/8) waves)
#define ASUB 782           // passA sub-blocks (ceil(3.2M/4096))

typedef unsigned long long u64;
typedef unsigned int u32;
typedef unsigned short u16;
typedef __attribute__((ext_vector_type(8))) short bf16x8;
typedef __attribute__((ext_vector_type(4))) float f32x4;

// ---------------------------------------------------------------------------
// helpers
// ---------------------------------------------------------------------------
__device__ __forceinline__ float wave_sum(float v) {
#pragma unroll
    for (int m = 1; m < 64; m <<= 1) v += __shfl_xor(v, m, 64);
    return v;
}

__device__ __forceinline__ u16 f2bf_rne(float f) {
    u32 u = __float_as_uint(f);
    u32 r = ((u >> 16) & 1u) + 0x7FFFu;
    return (u16)((u + r) >> 16);
}

__device__ __forceinline__ float bf2f(u32 bits16) {
    return __uint_as_float(bits16 << 16);
}

// ---------------------------------------------------------------------------
// 1) FUSED gemm + passA, parity-interleaved so both types co-reside per CU:
//    even blockIdx -> gemm (MFMA/HBM-bound), odd -> passA (LDS/VALU-bound).
//    Shared LDS arena: max(gemm 32 KB, passA 42 KB) = 42 KB -> 3 blocks/CU.
// ---------------------------------------------------------------------------
__global__ __launch_bounds__(512, 6) void fused_kernel(const float* __restrict__ feats,
                                                       const float* __restrict__ W,
                                                       u16* __restrict__ xwb,
                                                       const int* __restrict__ erow,
                                                       const int* __restrict__ ecol,
                                                       const float* __restrict__ eval,
                                                       u32* __restrict__ gcursor,
                                                       u64* __restrict__ sorted) {
    __shared__ u64 smem[5376];        // 43008 B arena
    const int tid = threadIdx.x;
    const int type = blockIdx.x & 1;
    const int sub = blockIdx.x >> 1;

    if (type == 0) {
        // ---------------- gemm: 8 waves x 16 rows = 128 rows per block ------
        u16* wlds = (u16*)smem;       // 32 KB fragment-major W
        for (int idx = tid; idx < 32 * 64; idx += 512) {
            const int f = idx >> 6, lane = idx & 63;
            const int kt = f >> 2, nt = f & 3;
            const int k0 = kt * 32 + (lane >> 4) * 8;
            const int n  = nt * 16 + (lane & 15);
            u32 buf[4];
#pragma unroll
            for (int jj = 0; jj < 4; ++jj) {
                u16 lo = f2bf_rne(W[(size_t)(k0 + 2 * jj) * EMB + n]);
                u16 hi = f2bf_rne(W[(size_t)(k0 + 2 * jj + 1) * EMB + n]);
                buf[jj] = (u32)lo | ((u32)hi << 16);
            }
            *(uint4*)&wlds[idx * 8] = *(uint4*)buf;
        }
        __syncthreads();

        const int wave = tid >> 6, lane = tid & 63;
        const int wid = sub * 8 + wave;
        if (wid >= MWAVES) return;
        const int row0 = wid * 16;
        const int arow = row0 + (lane & 15);
        const int kbase = (lane >> 4) * 8;
        const float* fr = feats + (size_t)arow * IN_DIM + kbase;

        f32x4 acc[4] = {};
        const u16* wl = &wlds[lane * 8];
#pragma unroll
        for (int half = 0; half < 2; ++half) {
            // 8 float4 A-loads issued together (one latency exposure/half)
            float4 av[8];
#pragma unroll
            for (int k2 = 0; k2 < 4; ++k2) {
                const int kt = half * 4 + k2;
                av[2 * k2]     = *(const float4*)(fr + kt * 32);
                av[2 * k2 + 1] = *(const float4*)(fr + kt * 32 + 4);
            }
#pragma unroll
            for (int k2 = 0; k2 < 4; ++k2) {
                const int kt = half * 4 + k2;
                float4 a0 = av[2 * k2], a1 = av[2 * k2 + 1];
                u32 ab[4];
                ab[0] = (u32)f2bf_rne(a0.x) | ((u32)f2bf_rne(a0.y) << 16);
                ab[1] = (u32)f2bf_rne(a0.z) | ((u32)f2bf_rne(a0.w) << 16);
                ab[2] = (u32)f2bf_rne(a1.x) | ((u32)f2bf_rne(a1.y) << 16);
                ab[3] = (u32)f2bf_rne(a1.z) | ((u32)f2bf_rne(a1.w) << 16);
                bf16x8 afrag = *(bf16x8*)ab;
#pragma unroll
                for (int nt = 0; nt < 4; ++nt) {
                    bf16x8 bfrag = *(const bf16x8*)&wl[(kt * 4 + nt) * 512];
                    acc[nt] = __builtin_amdgcn_mfma_f32_16x16x32_bf16(afrag, bfrag, acc[nt], 0, 0, 0);
                }
            }
        }
        const int rb = row0 + (lane >> 4) * 4;
        const int cb = lane & 15;
#pragma unroll
        for (int nt = 0; nt < 4; ++nt)
#pragma unroll
            for (int r = 0; r < 4; ++r)
                xwb[(size_t)(rb + r) * EMB + nt * 16 + cb] = f2bf_rne(acc[nt][r]);
    } else {
        // ---------------- passA: bucket 4096 edges into 128-row buckets -----
        u64* stage    = smem;                          // 4096 u64 = 32 KB
        u32* histoffs = (u32*)(smem + 4096);           // 1024 u32
        u32* cursor   = (u32*)(smem + 4608);           // 1024 u32
        u32* partial  = (u32*)(smem + 5120);           // 512 u32

        const int e0 = sub * EPB;
        const int total = min(EPB, N_EDGES - e0);

        for (int i = tid; i < 1024; i += 512) histoffs[i] = 0;
        __syncthreads();

        u64 ent[8];
        int eb[8];
#pragma unroll
        for (int j = 0; j < 8; ++j) {
            const int e = e0 + j * 512 + tid;
            if (e < N_EDGES) {
                const int r = erow[e];
                const int c = ecol[e];
                const u16 vb = f2bf_rne(eval[e]);
                ent[j] = (u64)(u32)r | ((u64)(u32)c << 17) | ((u64)vb << 34);
                eb[j] = r >> 7;
                atomicAdd(&histoffs[eb[j]], 1u);
            } else {
                eb[j] = -1;
            }
        }
        __syncthreads();

        // exclusive scan: 2 buckets/thread + Hillis-Steele on 512 partials
        const u32 c0 = histoffs[2 * tid], c1 = histoffs[2 * tid + 1];
        const u32 s = c0 + c1;
        partial[tid] = s;
        __syncthreads();
        for (int off = 1; off < 512; off <<= 1) {
            u32 x = (tid >= off) ? partial[tid - off] : 0;
            __syncthreads();
            partial[tid] += x;
            __syncthreads();
        }
        const u32 base = partial[tid] - s;
        histoffs[2 * tid] = base;       cursor[2 * tid] = base;
        histoffs[2 * tid + 1] = base + c0; cursor[2 * tid + 1] = base + c0;
        __syncthreads();

        // counting-sort into LDS stage
#pragma unroll
        for (int j = 0; j < 8; ++j) {
            if (eb[j] >= 0) {
                u32 pos = atomicAdd(&cursor[eb[j]], 1u);
                stage[pos] = ent[j];
            }
        }
        __syncthreads();

        // reserve global space; fold (gbase - offs) into cursor
        for (int b = tid; b < 1024; b += 512) {
            const u32 cnt = cursor[b] - histoffs[b];
            const u32 gb = cnt ? atomicAdd(&gcursor[b], cnt) : 0;
            cursor[b] = gb - histoffs[b];      // u32 wrap ok
        }
        __syncthreads();

        // coalesced write-out of bucket runs
        for (int i = tid; i < total; i += 512) {
            const u64 p = stage[i];
            const int b = (int)(p & 0x1FFFFu) >> 7;
            const u32 gpos = cursor[b] + (u32)i;
            if (gpos < BSTRIDE) sorted[(size_t)b * BSTRIDE + gpos] = p;
        }
    }
}

// ---------------------------------------------------------------------------
// 2) gather: one 512-thread block (8 waves) per 128-row bucket.
//    39 KB LDS -> 4 blocks/CU x 8 waves = 32 waves/CU, 782 blocks <= 1024
//    resident slots -> zero scheduling tail. Entries read ONCE into regs,
//    LDS row-sort, wave sweeps 16 rows (wave-uniform LDS reads + 8-wide
//    unrolled xw gathers). emb overlays the bucket's own dead region.
// ---------------------------------------------------------------------------
__global__ __launch_bounds__(512, 8) void gather_kernel(const u16* __restrict__ xwb,
                                                        u64* __restrict__ sorted,
                                                        const u32* __restrict__ gcursor,
                                                        float* __restrict__ accumA) {
    __shared__ u64 stage[BSTRIDE];    // 36864 B
    __shared__ u32 rhist[BROWS], roff[BROWS], rcur[BROWS], sc[BROWS];
    __shared__ float part[8];
    const int tid = threadIdx.x, wave = tid >> 6, lane = tid & 63;
    const int b = blockIdx.x;
    u64* gbase = sorted + (size_t)b * BSTRIDE;
    const int cnt = min((int)gcursor[b], BSTRIDE);

    if (tid < BROWS) rhist[tid] = 0;
    __syncthreads();

    // coalesced one-shot read into registers + histogram from registers
    u64 ent[9];                       // ceil(4608/512)
    int nloc = 0;
    for (int i = tid; i < cnt; i += 512) {
        u64 p = gbase[i];
        ent[nloc++] = p;
        atomicAdd(&rhist[(int)(p & 127u)], 1u);
    }
    __syncthreads();

    // exclusive scan of 128 row counts (threads 0..127)
    if (tid < BROWS) sc[tid] = rhist[tid];
    __syncthreads();
    for (int off = 1; off < BROWS; off <<= 1) {
        u32 x = (tid < BROWS && tid >= off) ? sc[tid - off] : 0;
        __syncthreads();
        if (tid < BROWS) sc[tid] += x;
        __syncthreads();
    }
    if (tid < BROWS) {
        roff[tid] = sc[tid] - rhist[tid];
        rcur[tid] = sc[tid] - rhist[tid];
    }
    __syncthreads();

    // scatter from registers into row-grouped LDS stage
    for (int j = 0; j < nloc; ++j) {
        const u64 p = ent[j];
        const u32 pos = atomicAdd(&rcur[(int)(p & 127u)], 1u);
        stage[pos] = p;
    }
    __syncthreads();

    // sweep: wave handles rows wave*16 .. wave*16+15
    u16* embp = (u16*)gbase;          // entries dead (staged in LDS)
    float wd = 0.f;
    for (int rr = 0; rr < 16; ++rr) {
        const int r = wave * 16 + rr;
        const int s0 = roff[r], n = rhist[r];
        float acc = 0.f;
        int j = s0;
        const int e2 = s0 + n;
        for (; j + 7 < e2; j += 8) {
            u64 p0 = stage[j],     p1 = stage[j + 1], p2 = stage[j + 2], p3 = stage[j + 3];
            u64 p4 = stage[j + 4], p5 = stage[j + 5], p6 = stage[j + 6], p7 = stage[j + 7];
            float x0 = bf2f(xwb[(size_t)((p0 >> 17) & 0x1FFFFu) * EMB + lane]);
            float x1 = bf2f(xwb[(size_t)((p1 >> 17) & 0x1FFFFu) * EMB + lane]);
            float x2 = bf2f(xwb[(size_t)((p2 >> 17) & 0x1FFFFu) * EMB + lane]);
            float x3 = bf2f(xwb[(size_t)((p3 >> 17) & 0x1FFFFu) * EMB + lane]);
            float x4 = bf2f(xwb[(size_t)((p4 >> 17) & 0x1FFFFu) * EMB + lane]);
            float x5 = bf2f(xwb[(size_t)((p5 >> 17) & 0x1FFFFu) * EMB + lane]);
            float x6 = bf2f(xwb[(size_t)((p6 >> 17) & 0x1FFFFu) * EMB + lane]);
            float x7 = bf2f(xwb[(size_t)((p7 >> 17) & 0x1FFFFu) * EMB + lane]);
            acc += bf2f((u32)(p0 >> 34) & 0xFFFFu) * x0 + bf2f((u32)(p1 >> 34) & 0xFFFFu) * x1;
            acc += bf2f((u32)(p2 >> 34) & 0xFFFFu) * x2 + bf2f((u32)(p3 >> 34) & 0xFFFFu) * x3;
            acc += bf2f((u32)(p4 >> 34) & 0xFFFFu) * x4 + bf2f((u32)(p5 >> 34) & 0xFFFFu) * x5;
            acc += bf2f((u32)(p6 >> 34) & 0xFFFFu) * x6 + bf2f((u32)(p7 >> 34) & 0xFFFFu) * x7;
        }
        for (; j < e2; ++j) {
            u64 p = stage[j];
            acc += bf2f((u32)(p >> 34) & 0xFFFFu) * bf2f(xwb[(size_t)((p >> 17) & 0x1FFFFu) * EMB + lane]);
        }
        float x = tanhf(acc);
        float sq = wave_sum(x * x);
        if (b * BROWS + r < N_NODES)
            embp[r * EMB + lane] = f2bf_rne(x * rsqrtf(fmaxf(sq, 1e-12f)));
        wd += sq / fmaxf(sq, 1e-12f);   // 0 for empty rows
    }
    if (lane == 0) part[wave] = wd;
    __syncthreads();
    if (tid == 0) {
        float v = 0.f;
#pragma unroll
        for (int w = 0; w < 8; ++w) v += part[w];
        unsafeAtomicAdd(&accumA[b & 255], v);
    }
}

// ---------------------------------------------------------------------------
// 3) BPR + fused finalize: emb lookup per sample; last block (device-scope
//    done counter) reduces accumA/accumB and writes the loss.
// ---------------------------------------------------------------------------
__device__ __forceinline__ float emb_ld(const u64* __restrict__ sorted, int row, int lane) {
    const u16* rp = (const u16*)(sorted + (size_t)(row >> 7) * BSTRIDE) + (row & 127) * EMB;
    return bf2f(rp[lane]);
}

__global__ __launch_bounds__(256) void bpr_kernel(const u64* __restrict__ sorted,
                                                  const int* __restrict__ idx1,
                                                  const int* __restrict__ idx2,
                                                  const int* __restrict__ nidx,
                                                  float* __restrict__ accumA,
                                                  float* __restrict__ accumB,
                                                  u32* __restrict__ done,
                                                  float* __restrict__ out) {
    __shared__ int lastflag;
    const int tid = threadIdx.x;
    const int wave = tid >> 6, lane = tid & 63;
    const int i = blockIdx.x * 4 + wave;
    float o1 = emb_ld(sorted, idx1[i], lane);
    float o2 = emb_ld(sorted, idx2[i], lane);
    float on = emb_ld(sorted, nidx[i], lane);
    float yui = wave_sum(o1 * o2);
    float yuj = wave_sum(o1 * on);
    if (lane == 0) {
        float x = yui - yuj;
        float li = (x > 0.f) ? log1pf(expf(-x)) : (-x + log1pf(expf(x)));
        unsafeAtomicAdd(&accumB[i & 255], li);
    }
    __threadfence();
    __syncthreads();
    if (tid == 0) lastflag = (atomicAdd(done, 1u) == (u32)(gridDim.x - 1)) ? 1 : 0;
    __syncthreads();
    if (lastflag && tid < 64) {
        float wd = 0.f, bp = 0.f;
#pragma unroll
        for (int k = 0; k < 4; ++k) {
            wd += accumA[tid + 64 * k];
            bp += accumB[tid + 64 * k];
        }
        wd = wave_sum(wd);
        bp = wave_sum(bp);
        if (tid == 0) out[0] = (bp + 1e-4f * 0.5f * wd) / (float)BATCH;
    }
}

extern "C" void kernel_launch(void* const* d_in, const int* in_sizes, int n_in,
                              void* d_out, int out_size, void* d_ws, size_t ws_size,
                              hipStream_t stream) {
    const float* feats = (const float*)d_in[0];
    const float* W     = (const float*)d_in[1];
    const int*   erow  = (const int*)d_in[2];
    const int*   ecol  = (const int*)d_in[3];
    const float* eval  = (const float*)d_in[4];
    const int*   idx1  = (const int*)d_in[5];
    const int*   idx2  = (const int*)d_in[6];
    const int*   nidx  = (const int*)d_in[7];
    float* out = (float*)d_out;

    // workspace layout (~41.7 MB)
    u16*   xwb     = (u16*)d_ws;                               // 12.8 MB
    u64*   sorted  = (u64*)(xwb + (size_t)N_NODES * EMB);      // 782*4608*8 = 28.8 MB
    u32*   gcursor = (u32*)(sorted + (size_t)NBUCK * BSTRIDE); // 1024
    float* accumA  = (float*)(gcursor + 1024);                 // 256
    float* accumB  = accumA + 256;                             // 256
    u32*   done    = (u32*)(accumB + 256);                     // 16

    hipMemsetAsync(gcursor, 0, (1024 + 256 + 256 + 16) * sizeof(u32), stream);

    fused_kernel<<<GSUB + ASUB, 512, 0, stream>>>(feats, W, xwb, erow, ecol, eval, gcursor, sorted);
    gather_kernel<<<NBUCK, 512, 0, stream>>>(xwb, sorted, gcursor, accumA);
    bpr_kernel<<<BATCH / 4, 256, 0, stream>>>(sorted, idx1, idx2, nidx, accumA, accumB, done, out);
}